// Round 7
// baseline (585.300 us; speedup 1.0000x reference)
//
#include <hip/hip_runtime.h>
#include <climits>
#include <cstdint>

// Round 9: decouple stream from sparse work (R8 post-mortem: bit-OR+MLP was
// NEUTRAL at 468.9 vs 466.1 -- issue-slot theory falsified. Two different
// coarse structures both ran ~2.2-2.4 TB/s => shared limiter: NT-flag and/or
// the cm-load/logf/accumulator chain inside the stream loop).
// R9: Kernel A = pure plain-load scan (matches the 6.29 TB/s m13 recipe) that
// only COMPACTS nonzero entries (~16K of 67M) via atomicAdd+store; Kernel B
// processes compacted entries (cm load + logf + atomicMin jv + partials).
// Overflow-safe: entries cap clamped to ws_size; past-cap hits processed
// inline via spill accumulator (never taken on these inputs).
// Prediction: A 45-55 us, B ~3, fine 10-20, finalize ~10 => total ~390-410.
//
// ws layout (bytes, 64-B aligned sections):
//   [0,4)    u32   gcnt        (memset 0)
//   [4,8)    float spill       (memset 0 -- same 8-B memset)
//   [64, 64+M*4)        int   jv[M]      sentinel 0x7F7F7F7F; valid iff < L
//   [.., +N*4)          float pnbuf[N]
//   [.., +BGRID*4)      float partialB[BGRID]
//   [64-B aligned)      Ent   ents[cap]  {u32 idx, f32 val}

typedef float    f32x4 __attribute__((ext_vector_type(4)));
typedef unsigned u32x4 __attribute__((ext_vector_type(4)));

static constexpr int      AGRID   = 2048;
static constexpr int      DEPTH   = 8;
static constexpr int      BGRID   = 256;
static constexpr unsigned CAP_MAX = 4u << 20;   // 4M entries = 32 MB

struct Ent { unsigned idx; float val; };

// ---------- A: pure gt scan + compaction ----------
__global__ __launch_bounds__(256) void mc_scan(
    const float* __restrict__ gt, unsigned nvec, unsigned L,
    unsigned* __restrict__ gcnt, Ent* __restrict__ ents, unsigned cap,
    const float* __restrict__ cm, int* __restrict__ jv,
    float* __restrict__ spill)
{
    const unsigned stride = gridDim.x * blockDim.x;
    unsigned v = blockIdx.x * blockDim.x + threadIdx.x;
    const f32x4* __restrict__ g4 = reinterpret_cast<const f32x4*>(gt);

    for (; v + (DEPTH - 1u) * stride < nvec; v += (unsigned)DEPTH * stride) {
        f32x4 g[DEPTH];
        #pragma unroll
        for (int m = 0; m < DEPTH; ++m)
            g[m] = g4[v + (unsigned)m * stride];          // plain loads (m13 recipe)
        #pragma unroll
        for (int m = 0; m < DEPTH; ++m) {
            const u32x4 u = __builtin_bit_cast(u32x4, g[m]);
            if ((u.x | u.y | u.z | u.w) != 0u) {          // rare (~1/16 wave-steps)
                const unsigned e = (v + (unsigned)m * stride) << 2;
                #pragma unroll
                for (int k = 0; k < 4; ++k) {
                    const float gk = g[m][k];
                    if (gk != 0.0f) {
                        const unsigned idx = atomicAdd(gcnt, 1u);
                        if (idx < cap) {
                            ents[idx].idx = e + (unsigned)k;
                            ents[idx].val = gk;
                        } else {  // overflow fallback: process inline (correct, slow)
                            atomicAdd(spill, gk * logf(cm[e + k] + 1e-6f));
                            if (gk > 0.0f) {
                                const unsigned ee = e + (unsigned)k;
                                const unsigned row = ee / L;
                                atomicMin(&jv[row], (int)(ee - row * L));
                            }
                        }
                    }
                }
            }
        }
    }
    for (; v < nvec; v += stride) {
        const f32x4 g = g4[v];
        const u32x4 u = __builtin_bit_cast(u32x4, g);
        if ((u.x | u.y | u.z | u.w) != 0u) {
            const unsigned e = v << 2;
            #pragma unroll
            for (int k = 0; k < 4; ++k) {
                const float gk = g[k];
                if (gk != 0.0f) {
                    const unsigned idx = atomicAdd(gcnt, 1u);
                    if (idx < cap) {
                        ents[idx].idx = e + (unsigned)k;
                        ents[idx].val = gk;
                    } else {
                        atomicAdd(spill, gk * logf(cm[e + k] + 1e-6f));
                        if (gk > 0.0f) {
                            const unsigned ee = e + (unsigned)k;
                            const unsigned row = ee / L;
                            atomicMin(&jv[row], (int)(ee - row * L));
                        }
                    }
                }
            }
        }
    }
}

// ---------- B: process compacted hits ----------
__global__ __launch_bounds__(256) void mc_hits(
    const Ent* __restrict__ ents, const unsigned* __restrict__ gcnt,
    unsigned cap, const float* __restrict__ cm, unsigned L,
    int* __restrict__ jv, float* __restrict__ partial)
{
    const unsigned n = min(*gcnt, cap);
    float local = 0.0f;
    for (unsigned i = blockIdx.x * blockDim.x + threadIdx.x; i < n;
         i += gridDim.x * blockDim.x) {
        const Ent t = ents[i];
        local += t.val * logf(cm[t.idx] + 1e-6f);
        if (t.val > 0.0f) {
            const unsigned row = t.idx / L;
            atomicMin(&jv[row], (int)(t.idx - row * L));
        }
    }
    #pragma unroll
    for (int o = 32; o; o >>= 1) local += __shfl_down(local, o);
    __shared__ float sc[4];
    if ((threadIdx.x & 63) == 0) sc[threadIdx.x >> 6] = local;
    __syncthreads();
    if (threadIdx.x == 0) partial[blockIdx.x] = sc[0] + sc[1] + sc[2] + sc[3];
}

// ---------- fine: one 256-thread block per point; result to pnbuf ----------
__global__ __launch_bounds__(256) void mc_fine_kernel(
    const float* __restrict__ s0, const float* __restrict__ s1,
    const float* __restrict__ mk0, const float* __restrict__ mk1,
    const int* __restrict__ jv, int B, int L,
    float* __restrict__ pnbuf)
{
    const int n = blockIdx.x;
    const float bf = mk0[3 * n + 0];
    const float x  = mk0[3 * n + 1];
    const float y  = mk0[3 * n + 2];
    const int b = (int)bf;

    int best = INT_MAX;
    if ((float)b == bf && b >= 0 && b < B) {
        const float2* __restrict__ srow = reinterpret_cast<const float2*>(s0 + (size_t)b * L * 2);
        const int*    __restrict__ jrow = jv + (size_t)b * L;
        #pragma unroll 4
        for (int i = threadIdx.x; i < L; i += 256) {
            const float2 s = srow[i];
            if (s.x == x && s.y == y && jrow[i] < L) best = min(best, i);
        }
    }
    #pragma unroll
    for (int o = 32; o; o >>= 1) best = min(best, __shfl_down(best, o));

    __shared__ int sb[4];
    if ((threadIdx.x & 63) == 0) sb[threadIdx.x >> 6] = best;
    __syncthreads();

    if (threadIdx.x == 0) {
        best = min(min(sb[0], sb[1]), min(sb[2], sb[3]));
        float res = -1.0f;
        if (best != INT_MAX) {
            const int j = jv[(size_t)b * L + best];
            const float gx = s1[((size_t)b * L + j) * 2 + 0];
            const float gy = s1[((size_t)b * L + j) * 2 + 1];
            const float dx = gx - mk1[2 * n + 0];
            const float dy = gy - mk1[2 * n + 1];
            const float pn = sqrtf(dx * dx + dy * dy);
            if (pn < 10.0f) res = pn;
        }
        pnbuf[n] = res;
    }
}

// ---------- finalize ----------
__global__ __launch_bounds__(1024) void mc_finalize_kernel(
    const float* __restrict__ partial, int P,
    const float* __restrict__ spill,
    const int* __restrict__ jv, int M,
    const float* __restrict__ pnbuf, int N,
    float binv, int L, float* __restrict__ out)
{
    float csum = 0.0f, fsum = 0.0f;
    int vcnt = 0, fcnt = 0;
    for (int i = threadIdx.x; i < P; i += 1024) csum += partial[i];
    for (int i = threadIdx.x; i < M; i += 1024) vcnt += (jv[i] < L) ? 1 : 0;
    for (int i = threadIdx.x; i < N; i += 1024) {
        const float p = pnbuf[i];
        if (p >= 0.0f) { fsum += p; ++fcnt; }
    }
    #pragma unroll
    for (int o = 32; o; o >>= 1) {
        csum += __shfl_down(csum, o);
        vcnt += __shfl_down(vcnt, o);
        fsum += __shfl_down(fsum, o);
        fcnt += __shfl_down(fcnt, o);
    }
    __shared__ float sc[16], sf[16];
    __shared__ int   sv[16], sn[16];
    const int wid = threadIdx.x >> 6, lane = threadIdx.x & 63;
    if (lane == 0) { sc[wid] = csum; sv[wid] = vcnt; sf[wid] = fsum; sn[wid] = fcnt; }
    __syncthreads();
    if (threadIdx.x == 0) {
        float C = *spill, F = 0.0f; int V = 0, K = 0;
        const int nw = blockDim.x >> 6;
        for (int w = 0; w < nw; ++w) { C += sc[w]; V += sv[w]; F += sf[w]; K += sn[w]; }
        const float coarse = -C * binv;
        const float fine = (V > 0) ? ((K > 0) ? F / (float)K : 10.0f) : 1e-6f;
        out[0] = coarse + 1000.0f * fine;
        out[1] = coarse;
        out[2] = fine;
    }
}

extern "C" void kernel_launch(void* const* d_in, const int* in_sizes, int n_in,
                              void* d_out, int out_size, void* d_ws, size_t ws_size,
                              hipStream_t stream) {
    const float* cm  = (const float*)d_in[0];  // [B,L,L]
    const float* gt  = (const float*)d_in[1];  // [B,L,L]
    const float* s0  = (const float*)d_in[2];  // [B,L,2]
    const float* s1  = (const float*)d_in[3];  // [B,L,2]
    const float* mk0 = (const float*)d_in[4];  // [N,3]
    const float* mk1 = (const float*)d_in[5];  // [N,2]
    float* out = (float*)d_out;

    // in_sizes are ELEMENT counts.
    const int L = 2 * (in_sizes[0] / in_sizes[2]);
    const int B = in_sizes[2] / (2 * L);
    const int N = in_sizes[4] / 3;
    const int M = B * L;
    const unsigned nvec = (unsigned)(in_sizes[0] >> 2);  // float4 count of gt

    // ws carve-up
    char* p = (char*)d_ws;
    unsigned* gcnt  = (unsigned*)p;                 // [0,4)
    float*    spill = (float*)(p + 4);              // [4,8)
    int*      jv    = (int*)(p + 64);
    float*    pnbuf = (float*)(p + 64 + (size_t)M * 4);
    float*    partB = (float*)(p + 64 + (size_t)M * 4 + (size_t)N * 4);
    size_t ents_off = 64 + (size_t)M * 4 + (size_t)N * 4 + (size_t)BGRID * 4;
    ents_off = (ents_off + 63) & ~(size_t)63;
    Ent* ents = (Ent*)(p + ents_off);
    unsigned cap = 0;
    if (ws_size > ents_off + 8)
        cap = (unsigned)min((size_t)CAP_MAX, (ws_size - ents_off) / 8);

    hipMemsetAsync(gcnt, 0, 8, stream);                    // gcnt + spill
    hipMemsetAsync(jv, 0x7F, (size_t)M * 4, stream);       // sentinel

    mc_scan<<<AGRID, 256, 0, stream>>>(gt, nvec, (unsigned)L, gcnt, ents, cap,
                                       cm, jv, spill);
    mc_hits<<<BGRID, 256, 0, stream>>>(ents, gcnt, cap, cm, (unsigned)L, jv, partB);
    mc_fine_kernel<<<N, 256, 0, stream>>>(s0, s1, mk0, mk1, jv, B, L, pnbuf);
    mc_finalize_kernel<<<1, 1024, 0, stream>>>(partB, BGRID, spill, jv, M, pnbuf, N,
                                               1.0f / (float)B, L, out);
}

// Round 10
// 491.813 us; speedup vs baseline: 1.1901x; 1.1901x over previous
//
#include <hip/hip_runtime.h>
#include <climits>
#include <cstdint>

// Round 12: identical to R10/R11 (broker timeouts -- inline+plain has never
// executed; it is the single-variable NT test and must run unconfounded).
// Evidence ledger: R9's mc_scan (202us, VALUBusy 1.5%, HBM 8.4%) proved
// same-line returning atomics serialize (~12.5ns each; 2:1 vs R1's 32K=410us)
// AND that plain loads let L3 serve half of gt (FETCH=134MB of 268MB).
// R6/R8 used nontemporal loads and plateaued at ~2.2 TB/s -- NT defeats L3
// allocation by design. This kernel = inline structure (local accumulator,
// fire-and-forget scattered atomicMin, no counter) with ALL NT flags dropped.
// Prediction: coarse 45-70us (FETCH 134-200MB), total ~395-430us.
//
// ws layout (bytes):
//   [0,        M*4)          int   jv[B*L]   min col with gt>0, sentinel 0x7F7F7F7F
//   [M*4,      M*4+N*4)      float pnbuf[N]  pn if (found && pn<10) else -1
//   [M*4+N*4,  +CGRID*4)     float partial[CGRID] per-block coarse sums

typedef float    f32x4 __attribute__((ext_vector_type(4)));
typedef unsigned u32x4 __attribute__((ext_vector_type(4)));

static constexpr int CGRID = 2048;
static constexpr int DEPTH = 8;   // float4 loads in flight per thread

template <int LSHIFT>
__device__ __forceinline__ void coarse_proc4(
    float& local, const float* __restrict__ cm, int* __restrict__ jv,
    const f32x4 g, const unsigned v)
{
    // one branch per float4: bit-OR of the 4 words. Exact float checks inside.
    const u32x4 u = __builtin_bit_cast(u32x4, g);
    if ((u.x | u.y | u.z | u.w) != 0u) {
        constexpr unsigned LMASK = (1u << LSHIFT) - 1u;
        const unsigned e   = v << 2;          // element index (float4-aligned)
        const unsigned row = e >> LSHIFT;     // all 4 elems same row (L%4==0)
        const unsigned col = e & LMASK;
        #pragma unroll
        for (int k = 0; k < 4; ++k) {
            const float gk = g[k];
            if (gk != 0.0f) {
                local += gk * logf(cm[e + k] + 1e-6f);
                // non-returning atomicMin: fire-and-forget, no wave stall;
                // scattered addresses (one per row), not same-line.
                if (gk > 0.0f) atomicMin(&jv[row], (int)(col + (unsigned)k));
            }
        }
    }
}

__device__ __forceinline__ void coarse_proc4_gen(
    float& local, const float* __restrict__ cm, int* __restrict__ jv,
    const f32x4 g, const unsigned v, const unsigned L)
{
    const u32x4 u = __builtin_bit_cast(u32x4, g);
    if ((u.x | u.y | u.z | u.w) != 0u) {
        const unsigned e   = v << 2;
        const unsigned row = e / L;
        const unsigned col = e - row * L;
        #pragma unroll
        for (int k = 0; k < 4; ++k) {
            const float gk = g[k];
            if (gk != 0.0f) {
                local += gk * logf(cm[e + k] + 1e-6f);
                if (gk > 0.0f) atomicMin(&jv[row], (int)(col + (unsigned)k));
            }
        }
    }
}

template <int LSHIFT>
__global__ __launch_bounds__(256) void mc_coarse_flat(
    const float* __restrict__ cm, const float* __restrict__ gt,
    unsigned nvec, int* __restrict__ jv, float* __restrict__ partial)
{
    const unsigned stride = gridDim.x * blockDim.x;
    unsigned v = blockIdx.x * blockDim.x + threadIdx.x;
    const f32x4* __restrict__ g4 = reinterpret_cast<const f32x4*>(gt);

    float local = 0.0f;

    // main loop: DEPTH plain float4 loads in flight, fully coalesced.
    // PLAIN (not nontemporal): lets L3 serve ~half of gt (R9: FETCH=134MB).
    for (; v + (DEPTH - 1u) * stride < nvec; v += (unsigned)DEPTH * stride) {
        f32x4 g[DEPTH];
        #pragma unroll
        for (int m = 0; m < DEPTH; ++m)
            g[m] = g4[v + (unsigned)m * stride];
        #pragma unroll
        for (int m = 0; m < DEPTH; ++m)
            coarse_proc4<LSHIFT>(local, cm, jv, g[m], v + (unsigned)m * stride);
    }
    for (; v < nvec; v += stride) {
        const f32x4 g = g4[v];
        coarse_proc4<LSHIFT>(local, cm, jv, g, v);
    }

    #pragma unroll
    for (int o = 32; o; o >>= 1) local += __shfl_down(local, o);
    __shared__ float sc[4];
    if ((threadIdx.x & 63) == 0) sc[threadIdx.x >> 6] = local;
    __syncthreads();
    if (threadIdx.x == 0) partial[blockIdx.x] = sc[0] + sc[1] + sc[2] + sc[3];
}

__global__ __launch_bounds__(256) void mc_coarse_flat_gen(
    const float* __restrict__ cm, const float* __restrict__ gt,
    unsigned nvec, unsigned L, int* __restrict__ jv, float* __restrict__ partial)
{
    const unsigned stride = gridDim.x * blockDim.x;
    unsigned v = blockIdx.x * blockDim.x + threadIdx.x;
    const f32x4* __restrict__ g4 = reinterpret_cast<const f32x4*>(gt);

    float local = 0.0f;
    for (; v + (DEPTH - 1u) * stride < nvec; v += (unsigned)DEPTH * stride) {
        f32x4 g[DEPTH];
        #pragma unroll
        for (int m = 0; m < DEPTH; ++m)
            g[m] = g4[v + (unsigned)m * stride];
        #pragma unroll
        for (int m = 0; m < DEPTH; ++m)
            coarse_proc4_gen(local, cm, jv, g[m], v + (unsigned)m * stride, L);
    }
    for (; v < nvec; v += stride) {
        const f32x4 g = g4[v];
        coarse_proc4_gen(local, cm, jv, g, v, L);
    }

    #pragma unroll
    for (int o = 32; o; o >>= 1) local += __shfl_down(local, o);
    __shared__ float sc[4];
    if ((threadIdx.x & 63) == 0) sc[threadIdx.x >> 6] = local;
    __syncthreads();
    if (threadIdx.x == 0) partial[blockIdx.x] = sc[0] + sc[1] + sc[2] + sc[3];
}

// ---------- fine: one 256-thread block per point; result to pnbuf ----------
__global__ __launch_bounds__(256) void mc_fine_kernel(
    const float* __restrict__ s0, const float* __restrict__ s1,
    const float* __restrict__ mk0, const float* __restrict__ mk1,
    const int* __restrict__ jv, int B, int L,
    float* __restrict__ pnbuf)
{
    const int n = blockIdx.x;
    const float bf = mk0[3 * n + 0];
    const float x  = mk0[3 * n + 1];
    const float y  = mk0[3 * n + 2];
    const int b = (int)bf;

    int best = INT_MAX;
    if ((float)b == bf && b >= 0 && b < B) {
        const float2* __restrict__ srow = reinterpret_cast<const float2*>(s0 + (size_t)b * L * 2);
        const int*    __restrict__ jrow = jv + (size_t)b * L;
        #pragma unroll 4
        for (int i = threadIdx.x; i < L; i += 256) {
            const float2 s = srow[i];
            if (s.x == x && s.y == y && jrow[i] < L) best = min(best, i);
        }
    }
    #pragma unroll
    for (int o = 32; o; o >>= 1) best = min(best, __shfl_down(best, o));

    __shared__ int sb[4];
    if ((threadIdx.x & 63) == 0) sb[threadIdx.x >> 6] = best;
    __syncthreads();

    if (threadIdx.x == 0) {
        best = min(min(sb[0], sb[1]), min(sb[2], sb[3]));
        float res = -1.0f;
        if (best != INT_MAX) {
            const int j = jv[(size_t)b * L + best];
            const float gx = s1[((size_t)b * L + j) * 2 + 0];
            const float gy = s1[((size_t)b * L + j) * 2 + 1];
            const float dx = gx - mk1[2 * n + 0];
            const float dy = gy - mk1[2 * n + 1];
            const float pn = sqrtf(dx * dx + dy * dy);
            if (pn < 10.0f) res = pn;
        }
        pnbuf[n] = res;
    }
}

// ---------- finalize: reduce block partials, jv validity, pnbuf ----------
__global__ __launch_bounds__(1024) void mc_finalize_kernel(
    const float* __restrict__ partial, int P,
    const int* __restrict__ jv, int M,
    const float* __restrict__ pnbuf, int N,
    float binv, int L, float* __restrict__ out)
{
    float csum = 0.0f, fsum = 0.0f;
    int vcnt = 0, fcnt = 0;
    for (int i = threadIdx.x; i < P; i += 1024) csum += partial[i];
    for (int i = threadIdx.x; i < M; i += 1024) vcnt += (jv[i] < L) ? 1 : 0;
    for (int i = threadIdx.x; i < N; i += 1024) {
        const float p = pnbuf[i];
        if (p >= 0.0f) { fsum += p; ++fcnt; }
    }
    #pragma unroll
    for (int o = 32; o; o >>= 1) {
        csum += __shfl_down(csum, o);
        vcnt += __shfl_down(vcnt, o);
        fsum += __shfl_down(fsum, o);
        fcnt += __shfl_down(fcnt, o);
    }
    __shared__ float sc[16], sf[16];
    __shared__ int   sv[16], sn[16];
    const int wid = threadIdx.x >> 6, lane = threadIdx.x & 63;
    if (lane == 0) { sc[wid] = csum; sv[wid] = vcnt; sf[wid] = fsum; sn[wid] = fcnt; }
    __syncthreads();
    if (threadIdx.x == 0) {
        float C = 0.0f, F = 0.0f; int V = 0, K = 0;
        const int nw = blockDim.x >> 6;
        for (int w = 0; w < nw; ++w) { C += sc[w]; V += sv[w]; F += sf[w]; K += sn[w]; }
        const float coarse = -C * binv;
        const float fine = (V > 0) ? ((K > 0) ? F / (float)K : 10.0f) : 1e-6f;
        out[0] = coarse + 1000.0f * fine;
        out[1] = coarse;
        out[2] = fine;
    }
}

extern "C" void kernel_launch(void* const* d_in, const int* in_sizes, int n_in,
                              void* d_out, int out_size, void* d_ws, size_t ws_size,
                              hipStream_t stream) {
    const float* cm  = (const float*)d_in[0];  // [B,L,L]
    const float* gt  = (const float*)d_in[1];  // [B,L,L]
    const float* s0  = (const float*)d_in[2];  // [B,L,2]
    const float* s1  = (const float*)d_in[3];  // [B,L,2]
    const float* mk0 = (const float*)d_in[4];  // [N,3]
    const float* mk1 = (const float*)d_in[5];  // [N,2]
    float* out = (float*)d_out;

    // in_sizes are ELEMENT counts.
    const int L = 2 * (in_sizes[0] / in_sizes[2]);
    const int B = in_sizes[2] / (2 * L);
    const int N = in_sizes[4] / 3;
    const int M = B * L;
    const unsigned nvec = (unsigned)(in_sizes[0] >> 2);  // float4 count of gt

    int*   jv      = (int*)d_ws;
    float* pnbuf   = (float*)((char*)d_ws + (size_t)M * 4);
    float* partial = (float*)((char*)d_ws + (size_t)M * 4 + (size_t)N * 4);

    // jv sentinel: 0x7F7F7F7F > any col; "valid" test everywhere is jv < L.
    hipMemsetAsync(jv, 0x7F, (size_t)M * 4, stream);

    if (L == 4096) {
        mc_coarse_flat<12><<<CGRID, 256, 0, stream>>>(cm, gt, nvec, jv, partial);
    } else {
        mc_coarse_flat_gen<<<CGRID, 256, 0, stream>>>(cm, gt, nvec, (unsigned)L, jv, partial);
    }
    mc_fine_kernel<<<N, 256, 0, stream>>>(s0, s1, mk0, mk1, jv, B, L, pnbuf);
    mc_finalize_kernel<<<1, 1024, 0, stream>>>(partial, CGRID, jv, M, pnbuf, N,
                                               1.0f / (float)B, L, out);
}

// Round 16
// 472.183 us; speedup vs baseline: 1.2396x; 1.0416x over previous
//
#include <hip/hip_runtime.h>
#include <climits>
#include <cstdint>

// Round 18: identical to R13-R17 (broker timeouts -- the vmcnt-clean
// LDS-queue kernel has never executed). Ledger: coarse stuck at ~110us
// (2.4 TB/s) across per-row (R2), flat+NT (R6), +bitOR+DEPTH8 (R8), plain
// loads (R10, WORSE by 23us -- NT kept). Two live theories:
//  (1) vmcnt pollution: in-loop device atomicMin/cm-loads share vmcnt with
//      the stream loads (FIFO drain) -- this kernel removes them from the loop.
//  (2) poison-fill writeback cap: the 2x 1GiB harness fills leave L2/L3 full
//      of dirty lines; any allocating read stream drags ~250MB of writeback
//      alongside our 268MB of reads (also explains plain<NT in R10).
// Discriminates: coarse 45-65us => (1); coarse unchanged ~105-115 => (2),
// and (2) means the coarse kernel is externally capped (floor ~450us total).
// Hits go to a per-block LDS queue (lgkmcnt domain); logf+cm+atomicMin run
// AFTER the stream on ~8 entries/block. Overflow -> inline fallback.
//
// ws layout (bytes):
//   [0,        M*4)          int   jv[B*L]   min col with gt>0, sentinel 0x7F7F7F7F
//   [M*4,      M*4+N*4)      float pnbuf[N]  pn if (found && pn<10) else -1
//   [M*4+N*4,  +CGRID*4)     float partial[CGRID] per-block coarse sums

typedef float    f32x4 __attribute__((ext_vector_type(4)));
typedef unsigned u32x4 __attribute__((ext_vector_type(4)));

static constexpr int CGRID = 2048;
static constexpr int DEPTH = 8;     // float4 loads in flight per thread
static constexpr int QCAP  = 1024;  // LDS queue entries (8 KB); ~8 expected

template <int LSHIFT>
__global__ __launch_bounds__(256) void mc_coarse_flat(
    const float* __restrict__ cm, const float* __restrict__ gt,
    unsigned nvec, int* __restrict__ jv, float* __restrict__ partial)
{
    constexpr unsigned LMASK = (1u << LSHIFT) - 1u;
    __shared__ unsigned qn;
    __shared__ unsigned qidx[QCAP];
    __shared__ float    qval[QCAP];
    if (threadIdx.x == 0) qn = 0;
    __syncthreads();

    const unsigned stride = gridDim.x * blockDim.x;
    unsigned v = blockIdx.x * blockDim.x + threadIdx.x;
    const f32x4* __restrict__ g4 = reinterpret_cast<const f32x4*>(gt);

    float local = 0.0f;

    // hot loop: NT loads + bit-OR predicate + LDS push on hit.
    // NO global atomics, NO logf, NO cm loads in here -- vmcnt stays
    // loads-only so waitcnt never drains a slow atomic.
    for (; v + (DEPTH - 1u) * stride < nvec; v += (unsigned)DEPTH * stride) {
        f32x4 g[DEPTH];
        #pragma unroll
        for (int m = 0; m < DEPTH; ++m)
            g[m] = __builtin_nontemporal_load(&g4[v + (unsigned)m * stride]);
        #pragma unroll
        for (int m = 0; m < DEPTH; ++m) {
            const u32x4 u = __builtin_bit_cast(u32x4, g[m]);
            if ((u.x | u.y | u.z | u.w) != 0u) {
                const unsigned e = (v + (unsigned)m * stride) << 2;
                #pragma unroll
                for (int k = 0; k < 4; ++k) {
                    const float gk = g[m][k];
                    if (gk != 0.0f) {
                        const unsigned qi = atomicAdd(&qn, 1u);   // LDS atomic
                        if (qi < (unsigned)QCAP) {
                            qidx[qi] = e + (unsigned)k;
                            qval[qi] = gk;
                        } else {  // overflow: inline fallback (dense gt only)
                            local += gk * logf(cm[e + k] + 1e-6f);
                            if (gk > 0.0f)
                                atomicMin(&jv[(e + k) >> LSHIFT],
                                          (int)((e + k) & LMASK));
                        }
                    }
                }
            }
        }
    }
    for (; v < nvec; v += stride) {
        const f32x4 g = __builtin_nontemporal_load(&g4[v]);
        const u32x4 u = __builtin_bit_cast(u32x4, g);
        if ((u.x | u.y | u.z | u.w) != 0u) {
            const unsigned e = v << 2;
            #pragma unroll
            for (int k = 0; k < 4; ++k) {
                const float gk = g[k];
                if (gk != 0.0f) {
                    const unsigned qi = atomicAdd(&qn, 1u);
                    if (qi < (unsigned)QCAP) {
                        qidx[qi] = e + (unsigned)k;
                        qval[qi] = gk;
                    } else {
                        local += gk * logf(cm[e + k] + 1e-6f);
                        if (gk > 0.0f)
                            atomicMin(&jv[(e + k) >> LSHIFT],
                                      (int)((e + k) & LMASK));
                    }
                }
            }
        }
    }

    // flush the queue: sparse cm loads + logf + scattered fire-and-forget
    // atomicMin, all OUTSIDE the stream.
    __syncthreads();
    const unsigned n = min(qn, (unsigned)QCAP);
    for (unsigned i = threadIdx.x; i < n; i += 256) {
        const unsigned idx = qidx[i];
        const float    gv  = qval[i];
        local += gv * logf(cm[idx] + 1e-6f);
        if (gv > 0.0f) atomicMin(&jv[idx >> LSHIFT], (int)(idx & LMASK));
    }

    #pragma unroll
    for (int o = 32; o; o >>= 1) local += __shfl_down(local, o);
    __shared__ float sc[4];
    if ((threadIdx.x & 63) == 0) sc[threadIdx.x >> 6] = local;
    __syncthreads();
    if (threadIdx.x == 0) partial[blockIdx.x] = sc[0] + sc[1] + sc[2] + sc[3];
}

__global__ __launch_bounds__(256) void mc_coarse_flat_gen(
    const float* __restrict__ cm, const float* __restrict__ gt,
    unsigned nvec, unsigned L, int* __restrict__ jv, float* __restrict__ partial)
{
    __shared__ unsigned qn;
    __shared__ unsigned qidx[QCAP];
    __shared__ float    qval[QCAP];
    if (threadIdx.x == 0) qn = 0;
    __syncthreads();

    const unsigned stride = gridDim.x * blockDim.x;
    unsigned v = blockIdx.x * blockDim.x + threadIdx.x;
    const f32x4* __restrict__ g4 = reinterpret_cast<const f32x4*>(gt);

    float local = 0.0f;
    for (; v < nvec; v += stride) {
        const f32x4 g = __builtin_nontemporal_load(&g4[v]);
        const u32x4 u = __builtin_bit_cast(u32x4, g);
        if ((u.x | u.y | u.z | u.w) != 0u) {
            const unsigned e = v << 2;
            #pragma unroll
            for (int k = 0; k < 4; ++k) {
                const float gk = g[k];
                if (gk != 0.0f) {
                    const unsigned qi = atomicAdd(&qn, 1u);
                    if (qi < (unsigned)QCAP) {
                        qidx[qi] = e + (unsigned)k;
                        qval[qi] = gk;
                    } else {
                        const unsigned ee = e + (unsigned)k;
                        const unsigned row = ee / L;
                        local += gk * logf(cm[ee] + 1e-6f);
                        if (gk > 0.0f) atomicMin(&jv[row], (int)(ee - row * L));
                    }
                }
            }
        }
    }

    __syncthreads();
    const unsigned n = min(qn, (unsigned)QCAP);
    for (unsigned i = threadIdx.x; i < n; i += 256) {
        const unsigned idx = qidx[i];
        const float    gv  = qval[i];
        const unsigned row = idx / L;
        local += gv * logf(cm[idx] + 1e-6f);
        if (gv > 0.0f) atomicMin(&jv[row], (int)(idx - row * L));
    }

    #pragma unroll
    for (int o = 32; o; o >>= 1) local += __shfl_down(local, o);
    __shared__ float sc[4];
    if ((threadIdx.x & 63) == 0) sc[threadIdx.x >> 6] = local;
    __syncthreads();
    if (threadIdx.x == 0) partial[blockIdx.x] = sc[0] + sc[1] + sc[2] + sc[3];
}

// ---------- fine: one 256-thread block per point; result to pnbuf ----------
__global__ __launch_bounds__(256) void mc_fine_kernel(
    const float* __restrict__ s0, const float* __restrict__ s1,
    const float* __restrict__ mk0, const float* __restrict__ mk1,
    const int* __restrict__ jv, int B, int L,
    float* __restrict__ pnbuf)
{
    const int n = blockIdx.x;
    const float bf = mk0[3 * n + 0];
    const float x  = mk0[3 * n + 1];
    const float y  = mk0[3 * n + 2];
    const int b = (int)bf;

    int best = INT_MAX;
    if ((float)b == bf && b >= 0 && b < B) {
        const float2* __restrict__ srow = reinterpret_cast<const float2*>(s0 + (size_t)b * L * 2);
        const int*    __restrict__ jrow = jv + (size_t)b * L;
        #pragma unroll 4
        for (int i = threadIdx.x; i < L; i += 256) {
            const float2 s = srow[i];
            if (s.x == x && s.y == y && jrow[i] < L) best = min(best, i);
        }
    }
    #pragma unroll
    for (int o = 32; o; o >>= 1) best = min(best, __shfl_down(best, o));

    __shared__ int sb[4];
    if ((threadIdx.x & 63) == 0) sb[threadIdx.x >> 6] = best;
    __syncthreads();

    if (threadIdx.x == 0) {
        best = min(min(sb[0], sb[1]), min(sb[2], sb[3]));
        float res = -1.0f;
        if (best != INT_MAX) {
            const int j = jv[(size_t)b * L + best];
            const float gx = s1[((size_t)b * L + j) * 2 + 0];
            const float gy = s1[((size_t)b * L + j) * 2 + 1];
            const float dx = gx - mk1[2 * n + 0];
            const float dy = gy - mk1[2 * n + 1];
            const float pn = sqrtf(dx * dx + dy * dy);
            if (pn < 10.0f) res = pn;
        }
        pnbuf[n] = res;
    }
}

// ---------- finalize: reduce block partials, jv validity, pnbuf ----------
__global__ __launch_bounds__(1024) void mc_finalize_kernel(
    const float* __restrict__ partial, int P,
    const int* __restrict__ jv, int M,
    const float* __restrict__ pnbuf, int N,
    float binv, int L, float* __restrict__ out)
{
    float csum = 0.0f, fsum = 0.0f;
    int vcnt = 0, fcnt = 0;
    for (int i = threadIdx.x; i < P; i += 1024) csum += partial[i];
    for (int i = threadIdx.x; i < M; i += 1024) vcnt += (jv[i] < L) ? 1 : 0;
    for (int i = threadIdx.x; i < N; i += 1024) {
        const float p = pnbuf[i];
        if (p >= 0.0f) { fsum += p; ++fcnt; }
    }
    #pragma unroll
    for (int o = 32; o; o >>= 1) {
        csum += __shfl_down(csum, o);
        vcnt += __shfl_down(vcnt, o);
        fsum += __shfl_down(fsum, o);
        fcnt += __shfl_down(fcnt, o);
    }
    __shared__ float sc[16], sf[16];
    __shared__ int   sv[16], sn[16];
    const int wid = threadIdx.x >> 6, lane = threadIdx.x & 63;
    if (lane == 0) { sc[wid] = csum; sv[wid] = vcnt; sf[wid] = fsum; sn[wid] = fcnt; }
    __syncthreads();
    if (threadIdx.x == 0) {
        float C = 0.0f, F = 0.0f; int V = 0, K = 0;
        const int nw = blockDim.x >> 6;
        for (int w = 0; w < nw; ++w) { C += sc[w]; V += sv[w]; F += sf[w]; K += sn[w]; }
        const float coarse = -C * binv;
        const float fine = (V > 0) ? ((K > 0) ? F / (float)K : 10.0f) : 1e-6f;
        out[0] = coarse + 1000.0f * fine;
        out[1] = coarse;
        out[2] = fine;
    }
}

extern "C" void kernel_launch(void* const* d_in, const int* in_sizes, int n_in,
                              void* d_out, int out_size, void* d_ws, size_t ws_size,
                              hipStream_t stream) {
    const float* cm  = (const float*)d_in[0];  // [B,L,L]
    const float* gt  = (const float*)d_in[1];  // [B,L,L]
    const float* s0  = (const float*)d_in[2];  // [B,L,2]
    const float* s1  = (const float*)d_in[3];  // [B,L,2]
    const float* mk0 = (const float*)d_in[4];  // [N,3]
    const float* mk1 = (const float*)d_in[5];  // [N,2]
    float* out = (float*)d_out;

    // in_sizes are ELEMENT counts.
    const int L = 2 * (in_sizes[0] / in_sizes[2]);
    const int B = in_sizes[2] / (2 * L);
    const int N = in_sizes[4] / 3;
    const int M = B * L;
    const unsigned nvec = (unsigned)(in_sizes[0] >> 2);  // float4 count of gt

    int*   jv      = (int*)d_ws;
    float* pnbuf   = (float*)((char*)d_ws + (size_t)M * 4);
    float* partial = (float*)((char*)d_ws + (size_t)M * 4 + (size_t)N * 4);

    // jv sentinel: 0x7F7F7F7F > any col; "valid" test everywhere is jv < L.
    hipMemsetAsync(jv, 0x7F, (size_t)M * 4, stream);

    if (L == 4096) {
        mc_coarse_flat<12><<<CGRID, 256, 0, stream>>>(cm, gt, nvec, jv, partial);
    } else {
        mc_coarse_flat_gen<<<CGRID, 256, 0, stream>>>(cm, gt, nvec, (unsigned)L, jv, partial);
    }
    mc_fine_kernel<<<N, 256, 0, stream>>>(s0, s1, mk0, mk1, jv, B, L, pnbuf);
    mc_finalize_kernel<<<1, 1024, 0, stream>>>(partial, CGRID, jv, M, pnbuf, N,
                                               1.0f / (float)B, L, out);
}